// Round 5
// baseline (505.218 us; speedup 1.0000x reference)
//
#include <hip/hip_runtime.h>
#include <hip/hip_bf16.h>
#include <math.h>

#define B_    2
#define S_    2048
#define DIN   2048
#define DOUT  2048
#define H_    16
#define RD_   64
#define L_    512
#define HD_   128
#define BS_   (B_*S_)   // 4096

typedef __attribute__((ext_vector_type(8))) short bf16x8;
typedef __attribute__((ext_vector_type(4))) float f32x4;

__device__ __forceinline__ short f2bs(float f) {
    __hip_bfloat16 h = __float2bfloat16(f);
    return *reinterpret_cast<short*>(&h);
}
__device__ __forceinline__ float bs2f(short s) {
    unsigned u = ((unsigned)(unsigned short)s) << 16;
    return __uint_as_float(u);
}

// global -> LDS direct DMA, 16 B per lane. LDS dest is wave-uniform base
// (HW adds lane*16); global src is per-lane (enables source-side swizzle).
__device__ __forceinline__ void gld16(const void* g, void* l) {
    __builtin_amdgcn_global_load_lds(
        (const __attribute__((address_space(1))) unsigned int*)g,
        (__attribute__((address_space(3))) unsigned int*)l, 16, 0, 0);
}

// ---------------------------------------------------------------------------
// Fused fp32->bf16 cast of ALL inputs in ONE launch.
// ---------------------------------------------------------------------------
__global__ __launch_bounds__(256) void cast_all(
    const float* __restrict__ x,    const float* __restrict__ wq,
    const float* __restrict__ wkr,  const float* __restrict__ wdkv,
    const float* __restrict__ wo,   const float* __restrict__ wuk,
    const float* __restrict__ wuv,
    short* __restrict__ x_bf,   short* __restrict__ wqkr_bf,
    short* __restrict__ wdkv_bf, short* __restrict__ wo_bf,
    short* __restrict__ wuk_bf,  short* __restrict__ wuv_bf)
{
    long long i = (long long)blockIdx.x * 256 + threadIdx.x;  // 3,014,656 total
    const float* src; short* dst; long long off;
    if      (i < 1048576) { src = x;    dst = x_bf;              off = i; }
    else if (i < 1835008) { src = wq;   dst = wqkr_bf;           off = i - 1048576; }
    else if (i < 2097152) { src = wkr;  dst = wqkr_bf + 6291456; off = i - 1835008; }
    else if (i < 2228224) { src = wdkv; dst = wdkv_bf;           off = i - 2097152; }
    else if (i < 2752512) { src = wo;   dst = wo_bf;             off = i - 2228224; }
    else if (i < 2883584) { src = wuk;  dst = wuk_bf;            off = i - 2752512; }
    else                  { src = wuv;  dst = wuv_bf;            off = i - 2883584; }
    float4 a = ((const float4*)src)[off*2], b = ((const float4*)src)[off*2+1];
    bf16x8 t;
    t[0]=f2bs(a.x); t[1]=f2bs(a.y); t[2]=f2bs(a.z); t[3]=f2bs(a.w);
    t[4]=f2bs(b.x); t[5]=f2bs(b.y); t[6]=f2bs(b.z); t[7]=f2bs(b.w);
    ((bf16x8*)dst)[off] = t;
}

// ---------------------------------------------------------------------------
// bf16 MFMA NT GEMM (m97-structure). C[m][n] = sum_k A[m][k]*B[n][k].
// M=grid.y*128, K%32==0. az/bz/cz: gridDim.z batch strides (elements).
// ---------------------------------------------------------------------------
__global__ __launch_bounds__(256, 4) void gemm_bf(
    const short* __restrict__ A, const short* __restrict__ Bw,
    float* __restrict__ Cf, short* __restrict__ Cb, int N, int K,
    long long az, long long bz, long long cz)
{
    const int z = blockIdx.z;
    A  += (long long)z * az;
    Bw += (long long)z * bz;
    if (Cf) Cf += (long long)z * cz; else Cb += (long long)z * cz;

    __shared__ short As[128*32];
    __shared__ short Bs[128*32];
    const int tid = threadIdx.x;
    const int m0 = blockIdx.y << 7, n0 = blockIdx.x << 7;
    const int w = tid >> 6, lane = tid & 63;
    const int quad = lane >> 4, n16 = lane & 15;
    const int mw = (w & 1) << 6, nw = (w >> 1) << 6;
    const int lr = lane >> 2, cg = lane & 3;     // 16 rows x 4 col-groups
    const int swr = (quad ^ (n16 & 3)) << 3;     // frag-read swizzle (shorts)

    f32x4 acc[4][4];
    #pragma unroll
    for (int mt = 0; mt < 4; mt++)
        #pragma unroll
        for (int nt = 0; nt < 4; nt++) acc[mt][nt] = (f32x4){0.f,0.f,0.f,0.f};

    for (int k0 = 0; k0 < K; k0 += 32) {
        #pragma unroll
        for (int jj = 0; jj < 2; jj++) {
            int rb = (jj*4 + w)*16;              // wave-uniform row block
            int r = rb + lr;
            int sc = (cg ^ (r & 3)) << 3;        // source-side swizzle
            gld16(A  + (long long)(m0 + r)*K + k0 + sc, (void*)(As + rb*32));
            gld16(Bw + (long long)(n0 + r)*K + k0 + sc, (void*)(Bs + rb*32));
        }
        __syncthreads();                         // drains vmcnt before barrier
        bf16x8 af[4], bfr[4];
        #pragma unroll
        for (int t = 0; t < 4; t++) {
            af[t]  = *(const bf16x8*)(As + (mw + t*16 + n16)*32 + swr);
            bfr[t] = *(const bf16x8*)(Bs + (nw + t*16 + n16)*32 + swr);
        }
        #pragma unroll
        for (int mt = 0; mt < 4; mt++)
            #pragma unroll
            for (int nt = 0; nt < 4; nt++)
                acc[mt][nt] = __builtin_amdgcn_mfma_f32_16x16x32_bf16(
                                  af[mt], bfr[nt], acc[mt][nt], 0, 0, 0);
        __syncthreads();
    }

    #pragma unroll
    for (int mt = 0; mt < 4; mt++)
        #pragma unroll
        for (int nt = 0; nt < 4; nt++)
            #pragma unroll
            for (int r = 0; r < 4; r++) {
                long long row = m0 + mw + mt*16 + quad*4 + r;
                int col = n0 + nw + nt*16 + n16;
                if (Cf) Cf[row*(long long)N + col] = acc[mt][nt][r];
                else    Cb[row*(long long)N + col] = f2bs(acc[mt][nt][r]);
            }
}

// ---------------------------------------------------------------------------
// RMSNorm rows of 512 (fp32 in) -> bf16 out
// ---------------------------------------------------------------------------
__global__ __launch_bounds__(256) void rmsnorm_bf(const float* __restrict__ ckv,
                                                  const float* __restrict__ w,
                                                  short* __restrict__ out)
{
    const int row = blockIdx.x;
    const int tid = threadIdx.x;
    const float* p = ckv + (long long)row * L_;
    float v0 = p[tid], v1 = p[tid + 256];
    float ss = v0 * v0 + v1 * v1;
    #pragma unroll
    for (int o = 32; o >= 1; o >>= 1) ss += __shfl_xor(ss, o);
    __shared__ float wsum[4];
    if ((tid & 63) == 0) wsum[tid >> 6] = ss;
    __syncthreads();
    float tot = wsum[0] + wsum[1] + wsum[2] + wsum[3];
    float scale = rsqrtf(tot * (1.0f / (float)L_) + 1e-6f);
    out[(long long)row * L_ + tid]       = f2bs(v0 * scale * w[tid]);
    out[(long long)row * L_ + tid + 256] = f2bs(v1 * scale * w[tid + 256]);
}

// ---------------------------------------------------------------------------
// RoPE in place on the fused q/kr buffer qkr[BS][4096]:
//   q-rope cols 2048 + h*64 .. ; k-rope cols 3072 + h*64 ..
// ---------------------------------------------------------------------------
__global__ __launch_bounds__(256) void rope_kernel(short* __restrict__ qkr,
                                                   const int* __restrict__ offp)
{
    const int offset = offp[0];
    long long idx = (long long)blockIdx.x * 256 + threadIdx.x;  // (B*S)*H*32
    int r = (int)(idx & 31);
    long long t = idx >> 5;
    int h = (int)(t % H_);
    long long m = t / H_;
    int s = (int)(m % S_);

    float inv = __expf(-0.28782314f * (float)r);   // ln(10000)/32
    float ang = (float)(offset + s) * inv;
    float sn, cs;
    sincosf(ang, &sn, &cs);

    short* q = qkr + m * 4096 + 2048 + h * RD_;
    float x1 = bs2f(q[r]), x2 = bs2f(q[r + 32]);
    q[r]      = f2bs(x1 * cs - x2 * sn);
    q[r + 32] = f2bs(x2 * cs + x1 * sn);

    short* kk = qkr + m * 4096 + 3072 + h * RD_;
    x1 = bs2f(kk[r]); x2 = bs2f(kk[r + 32]);
    kk[r]      = f2bs(x1 * cs - x2 * sn);
    kk[r + 32] = f2bs(x2 * cs + x1 * sn);
}

// ---------------------------------------------------------------------------
// flash_mha v4 (R10): occupancy-first restructure.
// Evidence R4: depth-2 pipeline = ZERO delta (143->140us); MfmaUtil 12.8 /
// VALUBusy 22 / Occupancy 12% -> the 8-wave single-resident block is
// barrier-locked into one phase at a time; MFMA and VALU pipes never
// overlap (no second block to co-schedule, m114 mechanism unavailable).
// v4: 256-thr blocks (4 waves, 64 q-rows), 32-token K/V tiles, 2 buffers:
// LDS = 2*20KB + P 5KB = 46,080 B -> 3 blocks/CU = 12 waves/CU. Independent
// blocks are phase-diverse -> softmax VALU overlaps other blocks' MFMA.
// Counted-vmcnt double buffer kept: 5 gld16/wave/tile, top wait vmcnt(5),
// stage(t+2) issued after the end-of-tile barrier into the freed buffer.
// Per-buffer (shorts): KC[32][128]@0  KR[32][64]@4096  VT[128][32]@6144.
// P: [16][40] per wave @20480+w*640. Reads XOR-deswizzle what staging
// pre-swizzled on the SOURCE side (granule ^= row&7 / d&3).
// ---------------------------------------------------------------------------
#define SB    10240
#define KROFF 4096
#define VOFF  6144
#define PPO   20480

__global__ __launch_bounds__(256, 3)
void flash_mha(
    const short* __restrict__ qkr,      // [BS][4096] bf16 (q 3072 | kr 1024), rotated
    const short* __restrict__ K_up,     // [BS][2048] bf16 (h*128+d cols)
    const short* __restrict__ V_upT,    // [B*2048][2048] bf16 (row=h*128+d, col=t)
    const int* __restrict__ offp,
    short* __restrict__ ctx_bf)         // [BS][2048] bf16
{
    __shared__ short lds[23040];
    const int offset = offp[0];
    const int bh = blockIdx.y;
    const int b = bh >> 4, h = bh & 15;
    const int r0 = (int)(gridDim.x - 1 - blockIdx.x) * 64;   // longest first
    const int tid = threadIdx.x;
    const int w = tid >> 6, lane = tid & 63;
    const int quad = lane >> 4, n16 = lane & 15;
    const int rx3 = (n16 & 7) << 3;          // KC/KR read deswizzle (shorts)
    const int vx3 = (n16 & 3) << 3;          // VT read deswizzle (shorts)
    const float scale = rsqrtf((float)(HD_ + RD_));

    const int l4 = lane >> 4, g16 = lane & 15;   // 4 rows of 256B
    const int l8 = lane >> 3, g8  = lane & 7;    // 8 rows of 128B
    const int l2 = lane >> 2, g4  = lane & 3;    // 16 rows of 64B

    const short* kc_src = K_up  + ((long long)b*S_)*2048 + h*HD_;
    const short* kr_src = qkr   + ((long long)b*S_)*4096 + 3072 + h*RD_;
    const short* vt_src = V_upT + ((long long)(b*S_ + h*HD_))*2048;

    // 5 gld16 per wave: KC 2 (4 rows each), KR 1 (8 rows), VT 2 (16 rows each)
    auto stage = [&](int tk, int bi) {
        short* base = lds + bi*SB;
        #pragma unroll
        for (int j = 0; j < 2; j++) {
            int r4 = (w*2 + j)*4;
            int row = r4 + l4;
            int gs = g16 ^ (row & 7);
            gld16(kc_src + (long long)(tk + row)*2048 + gs*8,
                  (void*)(base + r4*128));
        }
        {
            int row = w*8 + l8;
            gld16(kr_src + (long long)(tk + row)*4096 + (g8 ^ l8)*8,
                  (void*)(base + KROFF + w*512));
        }
        #pragma unroll
        for (int j = 0; j < 2; j++) {
            int d16 = (w*2 + j)*16;
            int d = d16 + l2;
            int gs = g4 ^ (d & 3);
            gld16(vt_src + (long long)d*2048 + tk + gs*8,
                  (void*)(base + VOFF + d16*32));
        }
    };

    // Q fragments (oldest vm ops; drained by tile-0's vmcnt wait)
    bf16x8 qf[6];
    {
        const short* qp = qkr + ((long long)(b*S_ + r0 + w*16 + n16))*4096;
        #pragma unroll
        for (int ks = 0; ks < 4; ks++)
            qf[ks] = *(const bf16x8*)(qp + h*HD_ + ks*32 + quad*8);
        qf[4] = *(const bf16x8*)(qp + 2048 + h*RD_ + quad*8);
        qf[5] = *(const bf16x8*)(qp + 2048 + h*RD_ + 32 + quad*8);
    }

    int tmax = r0 + 64 + offset;
    if (tmax > S_) tmax = S_;        // >= 64 always -> both prologue stages valid

    stage(0, 0);
    stage(32, 1);

    f32x4 Oacc[8];
    #pragma unroll
    for (int v = 0; v < 8; v++) Oacc[v] = (f32x4){0.f,0.f,0.f,0.f};
    float mrun[4] = {-INFINITY,-INFINITY,-INFINITY,-INFINITY};
    float lrun[4] = {0.f,0.f,0.f,0.f};   // lane-partial sums

    int bi = 0;
    for (int t0 = 0; t0 < tmax; t0 += 32) {
        // S(t0) landed; S(t0+32)'s 5 DMAs may stay in flight
        if (t0 + 32 < tmax) asm volatile("s_waitcnt vmcnt(5)" ::: "memory");
        else                asm volatile("s_waitcnt vmcnt(0)" ::: "memory");
        __builtin_amdgcn_s_barrier();
        __builtin_amdgcn_sched_barrier(0);

        const short* kcb = lds + bi*SB;
        const short* krb = kcb + KROFF;
        const short* vtb = kcb + VOFF;

        // ---- scores: S[16 rows][32 tok], K-dim 192 ----
        f32x4 Sf[2];
        #pragma unroll
        for (int nt = 0; nt < 2; nt++) {
            f32x4 a = {0.f,0.f,0.f,0.f};
            const short* kc = kcb + (nt*16 + n16)*128;
            #pragma unroll
            for (int ks = 0; ks < 4; ks++)
                a = __builtin_amdgcn_mfma_f32_16x16x32_bf16(
                        qf[ks], *(const bf16x8*)(kc + ((ks*32 + quad*8) ^ rx3)),
                        a, 0, 0, 0);
            const short* kr = krb + (nt*16 + n16)*64;
            a = __builtin_amdgcn_mfma_f32_16x16x32_bf16(
                    qf[4], *(const bf16x8*)(kr + ((quad*8) ^ rx3)), a, 0, 0, 0);
            a = __builtin_amdgcn_mfma_f32_16x16x32_bf16(
                    qf[5], *(const bf16x8*)(kr + ((32 + quad*8) ^ rx3)), a, 0, 0, 0);
            Sf[nt] = a;
        }

        // ---- softmax: defer-max, no cross-lane ops in the common path ----
        float e0[4][2], lm[4];
        const bool full = (t0 + 31 <= r0 + w*16 + offset);  // wave-uniform
        if (full) {
            #pragma unroll
            for (int r = 0; r < 4; r++) {
                float s0 = Sf[0][r]*scale, s1 = Sf[1][r]*scale;
                e0[r][0] = s0; e0[r][1] = s1;
                lm[r] = fmaxf(s0, s1);
            }
        } else {
            #pragma unroll
            for (int r = 0; r < 4; r++) {
                const int srow = r0 + w*16 + quad*4 + r;
                lm[r] = -INFINITY;
                #pragma unroll
                for (int nt = 0; nt < 2; nt++) {
                    int t = t0 + nt*16 + n16;
                    float s = (t <= srow + offset) ? Sf[nt][r]*scale : -INFINITY;
                    e0[r][nt] = s;
                    lm[r] = fmaxf(lm[r], s);
                }
            }
        }
        bool trig = (lm[0] > mrun[0] + 8.f) | (lm[1] > mrun[1] + 8.f)
                  | (lm[2] > mrun[2] + 8.f) | (lm[3] > mrun[3] + 8.f);
        if (__any((int)trig)) {          // rare after the first tile
            float al[4];
            #pragma unroll
            for (int r = 0; r < 4; r++) {
                float tm = lm[r];
                tm = fmaxf(tm, __shfl_xor(tm, 1));
                tm = fmaxf(tm, __shfl_xor(tm, 2));
                tm = fmaxf(tm, __shfl_xor(tm, 4));
                tm = fmaxf(tm, __shfl_xor(tm, 8));
                if (tm > mrun[r]) { al[r] = __expf(mrun[r] - tm); mrun[r] = tm; }
                else al[r] = 1.f;
            }
            #pragma unroll
            for (int v = 0; v < 8; v++) {
                Oacc[v][0] *= al[0]; Oacc[v][1] *= al[1];
                Oacc[v][2] *= al[2]; Oacc[v][3] *= al[3];
            }
            lrun[0] *= al[0]; lrun[1] *= al[1];
            lrun[2] *= al[2]; lrun[3] *= al[3];
        }
        #pragma unroll
        for (int r = 0; r < 4; r++) {
            float ps = 0.f;
            #pragma unroll
            for (int nt = 0; nt < 2; nt++) {
                float ex = __expf(e0[r][nt] - mrun[r]);
                ps += ex;
                lds[PPO + w*640 + (quad*4 + r)*40 + nt*16 + n16] = f2bs(ex);
            }
            lrun[r] += ps;               // lane-partial, no shuffle
        }

        // ---- PV: O[16 rows][128 dims] += P @ V ----  (P is wave-private)
        bf16x8 pf = *(const bf16x8*)(lds + PPO + w*640 + n16*40 + quad*8);
        const int vo = (quad*8) ^ vx3;
        #pragma unroll
        for (int v = 0; v < 8; v++) {
            const short* vb = vtb + (v*16 + n16)*32;
            Oacc[v] = __builtin_amdgcn_mfma_f32_16x16x32_bf16(
                          pf, *(const bf16x8*)(vb + vo), Oacc[v], 0, 0, 0);
        }

        // all waves done reading buffer bi -> safe to refill it
        __builtin_amdgcn_s_barrier();
        if (t0 + 64 < tmax) stage(t0 + 64, bi);
        bi ^= 1;
    }

    // ---- epilogue: one-time lrun reduce, then ctx = O/l direct store ----
    float inv[4];
    #pragma unroll
    for (int r = 0; r < 4; r++) {
        float s = lrun[r];
        s += __shfl_xor(s, 1);
        s += __shfl_xor(s, 2);
        s += __shfl_xor(s, 4);
        s += __shfl_xor(s, 8);
        inv[r] = 1.0f / s;
    }
    #pragma unroll
    for (int v = 0; v < 8; v++)
        #pragma unroll
        for (int r = 0; r < 4; r++) {
            long long row = (long long)b*S_ + r0 + w*16 + quad*4 + r;
            ctx_bf[row*2048 + h*HD_ + v*16 + n16] = f2bs(Oacc[v][r]*inv[r]);
        }
}

// ---------------------------------------------------------------------------
extern "C" void kernel_launch(void* const* d_in, const int* in_sizes, int n_in,
                              void* d_out, int out_size, void* d_ws, size_t ws_size,
                              hipStream_t stream)
{
    const float* x       = (const float*)d_in[0];
    const float* W_DKV   = (const float*)d_in[1];
    const float* W_KRope = (const float*)d_in[2];
    const float* W_Q     = (const float*)d_in[3];
    const float* W_UK    = (const float*)d_in[4];
    const float* W_UV    = (const float*)d_in[5];
    const float* W_O     = (const float*)d_in[6];
    const float* kvnw    = (const float*)d_in[7];
    const int*   offp    = (const int*)d_in[8];
    float* out = (float*)d_out;

    float* ws = (float*)d_ws;
    float* c_kv    = ws;                        // 2,097,152 f
    short* x_bf    = (short*)(c_kv + 2097152);  // 8,388,608
    short* qkr_bf  = x_bf    + 8388608;         // 16,777,216  [4096][4096]
    short* c_kv_bf = qkr_bf  + 16777216;        // 2,097,152
    short* wuk_bf  = c_kv_bf + 2097152;         // 1,048,576
    short* wuv_bf  = wuk_bf  + 1048576;         // 1,048,576
    short* wdkv_bf = wuv_bf  + 1048576;         // 1,048,576
    short* wqkr_bf = wdkv_bf + 1048576;         // 8,388,608  [4096][2048]
    short* wo_bf   = wqkr_bf + 8388608;         // 4,194,304
    short* ctx_bf  = wo_bf   + 4194304;         // 8,388,608
    short* V_upT   = ctx_bf  + 8388608;         // 8,388,608
    // alias (lifetimes disjoint on the sequential stream):
    short* K_up    = x_bf;      // x_bf dead after the two x-GEMMs
    // total ~122 MiB

    dim3 blk(256);

    // one fused cast
    cast_all<<<11776, blk, 0, stream>>>(
        x, W_Q, W_KRope, W_DKV, W_O, W_UK, W_UV,
        x_bf, wqkr_bf, wdkv_bf, wo_bf, wuk_bf, wuv_bf);

    // fused Q+KRope projection: [4096]x[4096] = x @ [W_Q;W_KRope]^T
    gemm_bf<<<dim3(32, 32), blk, 0, stream>>>(
        x_bf, wqkr_bf, nullptr, qkr_bf, 4096, 2048, 0, 0, 0);
    // c_kv (fp32 out for rmsnorm precision)
    gemm_bf<<<dim3(4, 32), blk, 0, stream>>>(
        x_bf, wdkv_bf, c_kv, nullptr, 512, 2048, 0, 0, 0);
    rmsnorm_bf<<<4096, blk, 0, stream>>>(c_kv, kvnw, c_kv_bf);

    // absorbed K/V up-projections (K_up overwrites x_bf region).
    gemm_bf<<<dim3(16, 32), blk, 0, stream>>>(
        c_kv_bf, wuk_bf, nullptr, K_up, 2048, 512, 0, 0, 0);
    // V_upT = W_UV @ c_kv^T, both batches in one launch via grid.z
    gemm_bf<<<dim3(16, 16, 2), blk, 0, stream>>>(
        wuv_bf, c_kv_bf, nullptr, V_upT, 2048, 512,
        0, (long long)S_*512, (long long)S_*2048);

    // RoPE in place on the fused buffer
    rope_kernel<<<8192, blk, 0, stream>>>(qkr_bf, offp);

    // flash attention -> ctx (bf16); 1024 blocks of 4 waves, 3 blocks/CU
    flash_mha<<<dim3(S_/64, B_*H_), dim3(256), 0, stream>>>(
        qkr_bf, K_up, V_upT, offp, ctx_bf);

    // out = ctx @ W_O^T (fp32 out)
    gemm_bf<<<dim3(16, 32), blk, 0, stream>>>(
        ctx_bf, wo_bf, out, nullptr, 2048, 2048, 0, 0, 0);
}